// Round 3
// baseline (268.656 us; speedup 1.0000x reference)
//
#include <hip/hip_runtime.h>

// AdEx neuron simulation: B=32, T=2000, D=1024.
// Serial in t, parallel over B*D = 32768 neurons. 1 thread = 1 neuron.
//
// Correctness strategy: spikes are binary & the threshold crossing is
// chaotic -> must reproduce the reference trajectory BITWISE. Ground
// truth = JAX/XLA:CPU f32. All +,-,*,/ are IEEE f32; the only impl-
// defined op is exp. XLA:CPU emits the Cephes/Eigen3 polynomial exp
// (GenerateVF32Exp in llvm_ir_runtime.cc):
//   fx = floor(x*log2e + 0.5); Cody-Waite C1=0.693359375,
//   C2=-2.12194440e-4; degree-5 poly Horner; y*x^2 + x + 1; * 2^fx.
// XLA allows FP contraction -> on the AVX2/FMA host the mul+add pairs
// fuse; we use explicit FMA at exactly those sites (VARIANT 0). The step
// arithmetic is made FMA-consistent the same way (V' = fma(dt,dV,V)).
//
// VARIANT ladder (compile-time): 0 = Cephes+FMA (this round),
// 1 = Cephes noFMA, 2 = numpy npyv Pade (tried R2, failed).
#define EXP_VARIANT 0

#define Bn 32
#define Tn 2000
#define Dn 1024
#define NEUR (Bn * Dn)     // 32768
#define UNR 16             // prefetch depth (2000 % 16 == 0 -> NB = 125)
#define NB (Tn / UNR)

__device__ __forceinline__ float ref_expf(float x) {
    #pragma clang fp contract(off)
#if EXP_VARIANT == 0
    // XLA:CPU / Eigen3 Cephes exp, FMA-contracted form.
    // Clamp [-88.376..., 88.376...] omitted: args in (-10.5, 40).
    const float LOG2EF = 1.44269504088896341f;
    const float C1 = 0.693359375f;         // ln2 hi
    const float C2 = -2.12194440e-4f;      // ln2 lo
    const float p0 = 1.9875691500e-4f;
    const float p1 = 1.3981999507e-3f;
    const float p2 = 8.3334519073e-3f;
    const float p3 = 4.1665795894e-2f;
    const float p4 = 1.6666665459e-1f;
    const float p5 = 5.0000001201e-1f;

    float fx = __builtin_floorf(__builtin_fmaf(x, LOG2EF, 0.5f));
    // x - fx*C1 -> fnmadd; x1 - fx*C2 -> fnmadd (C2 negative -> +|C2|)
    float xr = __builtin_fmaf(fx, -C1, x);
    xr = __builtin_fmaf(fx, -C2, xr);
    float z2 = xr * xr;
    float y = p0;
    y = __builtin_fmaf(y, xr, p1);
    y = __builtin_fmaf(y, xr, p2);
    y = __builtin_fmaf(y, xr, p3);
    y = __builtin_fmaf(y, xr, p4);
    y = __builtin_fmaf(y, xr, p5);
    y = __builtin_fmaf(y, z2, xr);
    y = y + 1.0f;
    const int n = (int)fx;                       // fx integral, exact
    const float scale = __int_as_float((n + 127) << 23);
    return y * scale;                            // exact power-of-2 mul
#elif EXP_VARIANT == 1
    // Cephes exp, strict no-FMA form.
    const float LOG2EF = 1.44269504088896341f;
    const float C1 = 0.693359375f;
    const float C2 = -2.12194440e-4f;
    const float p0 = 1.9875691500e-4f;
    const float p1 = 1.3981999507e-3f;
    const float p2 = 8.3334519073e-3f;
    const float p3 = 4.1665795894e-2f;
    const float p4 = 1.6666665459e-1f;
    const float p5 = 5.0000001201e-1f;
    float fx = __builtin_floorf(x * LOG2EF + 0.5f);
    float tmp = fx * C1;
    float z = fx * C2;
    float xr = x - tmp;
    xr = xr - z;
    float z2 = xr * xr;
    float y = p0;
    y = y * xr + p1;
    y = y * xr + p2;
    y = y * xr + p3;
    y = y * xr + p4;
    y = y * xr + p5;
    y = y * z2 + xr;
    y = y + 1.0f;
    const int n = (int)fx;
    const float scale = __int_as_float((n + 127) << 23);
    return y * scale;
#else
    // numpy npyv rational Pade (refuted in R2, kept for reference).
    const float LOG2E = 1.442695040888963407360f;
    const float CW_HI = -6.93145752e-1f;
    const float CW_LO = -1.42860677e-6f;
    const float P0 = 9.999999999980870924916e-01f;
    const float P1 = 7.257664613233124478488e-01f;
    const float P2 = 2.473615434895520810817e-01f;
    const float P3 = 5.114512081637298353406e-02f;
    const float P4 = 6.757896990527504603057e-03f;
    const float P5 = 5.082762527590693718096e-04f;
    const float Q1 = -2.742335390411667452936e-01f;
    const float Q2 = 2.159509375685829852307e-02f;
    float q = __builtin_rintf(x * LOG2E);
    float r = __builtin_fmaf(q, CW_HI, x);
    r = __builtin_fmaf(q, CW_LO, r);
    float num = __builtin_fmaf(P5, r, P4);
    num = __builtin_fmaf(num, r, P3);
    num = __builtin_fmaf(num, r, P2);
    num = __builtin_fmaf(num, r, P1);
    num = __builtin_fmaf(num, r, P0);
    float den = __builtin_fmaf(Q2, r, Q1);
    den = __builtin_fmaf(den, r, 1.0f);
    float poly = num / den;
    return __builtin_ldexpf(poly, (int)q);
#endif
}

// One reference step (simple path: a==0 && b==0 -> w stays +0.0 bitwise).
// FMA-consistent with XLA contraction:
//   - R*i_t add: R==1 -> fused == unfused (exact), use plain ops.
//   - -R*w term: w==+0 -> no-op, skipped.
//   - V' = fma(dt, dV, V): the one genuinely contraction-sensitive op.
__device__ __forceinline__ void step_simple(float& V, float i_t, float& spk_out,
                                            float E_L, float V_T, float Delta_T,
                                            float R, float tau_m, float V_spike,
                                            float V_reset, float dt) {
    #pragma clang fp contract(off)
    const float e  = ref_expf((V - V_T) / Delta_T);
    const float et = Delta_T * e;                 // *2: exact
    float nm = (-(V - E_L) + et);
    nm = nm + R * i_t;                            // R==1: fused==unfused
    const float dV = nm / tau_m;
    V = __builtin_fmaf(dt, dV, V);                // contracted V + dt*dV
    spk_out = (V >= V_spike) ? 1.0f : 0.0f;
    V = (V >= V_spike) ? V_reset : V;
}

__device__ __forceinline__ void step_general(float& V, float& w, float i_t, float& spk_out,
                                             float E_L, float V_T, float Delta_T,
                                             float R, float tau_m, float tau_w,
                                             float a, float b,
                                             float V_spike, float V_reset, float dt) {
    #pragma clang fp contract(off)
    const float e  = ref_expf((V - V_T) / Delta_T);
    const float et = Delta_T * e;
    float nm = (-(V - E_L) + et);
    nm = __builtin_fmaf(-R, w, nm);               // acc - R*w contracted
    nm = __builtin_fmaf(R, i_t, nm);              // acc + R*i_t contracted
    const float dV = nm / tau_m;
    V = __builtin_fmaf(dt, dV, V);
    const float dwn = __builtin_fmaf(a, (V - E_L), -w);   // a*(V-E_L) - w
    const float dw  = dwn / tau_w;
    w = __builtin_fmaf(dt, dw, w);
    spk_out = (V >= V_spike) ? 1.0f : 0.0f;
    const bool s = (V >= V_spike);
    V = s ? V_reset : V;
    w = s ? (w + b) : w;
}

__launch_bounds__(128, 1)
__global__ void adex_kernel(const float* __restrict__ I,
                            const float* __restrict__ params,
                            float* __restrict__ out) {
    #pragma clang fp contract(off)

    const float tau_m   = params[0];
    const float E_L     = params[1];
    const float V_T     = params[2];
    const float Delta_T = params[3];
    const float R       = params[4];
    const float tau_w   = params[5];
    const float a       = params[6];
    const float b       = params[7];
    const float V_reset = params[8];
    const float V_spike = params[9];
    const float dt      = params[10];

    const int n = blockIdx.x * blockDim.x + threadIdx.x;
    if (n >= NEUR) return;
    const int bb = n >> 10;          // / Dn
    const int dd = n & (Dn - 1);     // % Dn

    const float* Ip = I   + (size_t)bb * (size_t)(Tn * Dn) + dd;
    float*       Op = out + (size_t)bb * (size_t)(Tn * Dn) + dd;

    float V = E_L;
    float w = 0.0f;

    float bufA[UNR], bufB[UNR];

    // Prologue: load time-block 0.
    #pragma unroll
    for (int k = 0; k < UNR; ++k) bufA[k] = Ip[k * Dn];

    const bool simple = (a == 0.0f) && (b == 0.0f);

    if (simple) {
        for (int tb = 0; tb < NB; tb += 2) {
            if (tb + 1 < NB) {
                const float* p = Ip + (size_t)(tb + 1) * (UNR * Dn);
                #pragma unroll
                for (int k = 0; k < UNR; ++k) bufB[k] = p[k * Dn];
            }
            {
                float* o = Op + (size_t)tb * (UNR * Dn);
                #pragma unroll
                for (int k = 0; k < UNR; ++k) {
                    float spk;
                    step_simple(V, bufA[k], spk, E_L, V_T, Delta_T, R, tau_m,
                                V_spike, V_reset, dt);
                    o[k * Dn] = spk;
                }
            }
            if (tb + 2 < NB) {
                const float* p = Ip + (size_t)(tb + 2) * (UNR * Dn);
                #pragma unroll
                for (int k = 0; k < UNR; ++k) bufA[k] = p[k * Dn];
            }
            if (tb + 1 < NB) {
                float* o = Op + (size_t)(tb + 1) * (UNR * Dn);
                #pragma unroll
                for (int k = 0; k < UNR; ++k) {
                    float spk;
                    step_simple(V, bufB[k], spk, E_L, V_T, Delta_T, R, tau_m,
                                V_spike, V_reset, dt);
                    o[k * Dn] = spk;
                }
            }
        }
    } else {
        for (int tb = 0; tb < NB; tb += 2) {
            if (tb + 1 < NB) {
                const float* p = Ip + (size_t)(tb + 1) * (UNR * Dn);
                #pragma unroll
                for (int k = 0; k < UNR; ++k) bufB[k] = p[k * Dn];
            }
            {
                float* o = Op + (size_t)tb * (UNR * Dn);
                #pragma unroll
                for (int k = 0; k < UNR; ++k) {
                    float spk;
                    step_general(V, w, bufA[k], spk, E_L, V_T, Delta_T, R, tau_m,
                                 tau_w, a, b, V_spike, V_reset, dt);
                    o[k * Dn] = spk;
                }
            }
            if (tb + 2 < NB) {
                const float* p = Ip + (size_t)(tb + 2) * (UNR * Dn);
                #pragma unroll
                for (int k = 0; k < UNR; ++k) bufA[k] = p[k * Dn];
            }
            if (tb + 1 < NB) {
                float* o = Op + (size_t)(tb + 1) * (UNR * Dn);
                #pragma unroll
                for (int k = 0; k < UNR; ++k) {
                    float spk;
                    step_general(V, w, bufB[k], spk, E_L, V_T, Delta_T, R, tau_m,
                                 tau_w, a, b, V_spike, V_reset, dt);
                    o[k * Dn] = spk;
                }
            }
        }
    }
}

extern "C" void kernel_launch(void* const* d_in, const int* in_sizes, int n_in,
                              void* d_out, int out_size, void* d_ws, size_t ws_size,
                              hipStream_t stream) {
    const float* I      = (const float*)d_in[0];
    const float* params = (const float*)d_in[1];
    float*       out    = (float*)d_out;

    dim3 block(128);
    dim3 grid(NEUR / 128);  // 256 blocks -> 1 per CU
    adex_kernel<<<grid, block, 0, stream>>>(I, params, out);
}

// Round 4
// 187.655 us; speedup vs baseline: 1.4316x; 1.4316x over previous
//
#include <hip/hip_runtime.h>

// AdEx neuron simulation: B=32, T=2000, D=1024.
// Serial in t, parallel over B*D = 32768 neurons. 1 thread = 1 neuron.
//
// Numerics (PROVEN in R3, absmax 0.0): reproduce JAX/XLA:CPU f32 bitwise.
// exp = XLA:CPU Cephes/Eigen3 polynomial with FMA contraction; step ops
// IEEE f32 with contract(off); V' = fma(dt,dV,V).
//
// R4 = latency surgery (wall time = 2000 x dependent-chain, only 512 waves
// on 1024 SIMDs -> parallelism can't help). All transforms bitwise-exact:
//  - /Delta_T (pow2 divisor, runtime-detected)  -> exact multiply by 1/DT
//  - Delta_T*exp fold into the 2^n scale        -> exact (x2 commutes w/ RN)
//  - /tau_m -> Markstein 3-op with r=1.0f/tau_m hoisted (provably == IEEE div)
//  - R==1: R*i_t == i_t exact; w==+0 (a==b==0): -R*w term exact no-op
//  - reset-select speculation: next-step x and (E_L-V) computed from
//    pre-reset Vr in parallel with the spike compare, cndmask'd against
//    precomputed reset constants. -(Vr-E_L) == E_L-Vr bitwise (RN symmetry).
// Non-hot parameter combos fall back to the R3-proven plain-division path.

#define Bn 32
#define Tn 2000
#define Dn 1024
#define NEUR (Bn * Dn)     // 32768
#define UNR 16             // prefetch depth (2000 % 16 == 0 -> NB = 125)
#define NB (Tn / UNR)

// ---------- exp: XLA:CPU / Eigen Cephes, FMA-contracted (R3-proven) ----------
#define EXP_LOG2EF 1.44269504088896341f
#define EXP_C1 0.693359375f
#define EXP_C2 -2.12194440e-4f
#define EXP_P0 1.9875691500e-4f
#define EXP_P1 1.3981999507e-3f
#define EXP_P2 8.3334519073e-3f
#define EXP_P3 4.1665795894e-2f
#define EXP_P4 1.6666665459e-1f
#define EXP_P5 5.0000001201e-1f

__device__ __forceinline__ float ref_expf(float x) {
    #pragma clang fp contract(off)
    float fx = __builtin_floorf(__builtin_fmaf(x, EXP_LOG2EF, 0.5f));
    float xr = __builtin_fmaf(fx, -EXP_C1, x);
    xr = __builtin_fmaf(fx, -EXP_C2, xr);
    float z2 = xr * xr;
    float y = EXP_P0;
    y = __builtin_fmaf(y, xr, EXP_P1);
    y = __builtin_fmaf(y, xr, EXP_P2);
    y = __builtin_fmaf(y, xr, EXP_P3);
    y = __builtin_fmaf(y, xr, EXP_P4);
    y = __builtin_fmaf(y, xr, EXP_P5);
    y = __builtin_fmaf(y, z2, xr);
    y = y + 1.0f;
    const int n = (int)fx;
    return y * __int_as_float((n + 127) << 23);
}

// exp(x) * 2^kdt  (kdt = log2(Delta_T), Delta_T a power of 2): folds the
// Delta_T multiply into the exact 2^n scale. Bitwise == Delta_T * ref_expf(x).
__device__ __forceinline__ float ref_expf_scaled(float x, int kdt) {
    #pragma clang fp contract(off)
    float fx = __builtin_floorf(__builtin_fmaf(x, EXP_LOG2EF, 0.5f));
    float xr = __builtin_fmaf(fx, -EXP_C1, x);
    xr = __builtin_fmaf(fx, -EXP_C2, xr);
    float z2 = xr * xr;
    float y = EXP_P0;
    y = __builtin_fmaf(y, xr, EXP_P1);
    y = __builtin_fmaf(y, xr, EXP_P2);
    y = __builtin_fmaf(y, xr, EXP_P3);
    y = __builtin_fmaf(y, xr, EXP_P4);
    y = __builtin_fmaf(y, xr, EXP_P5);
    y = __builtin_fmaf(y, z2, xr);
    y = y + 1.0f;
    const int n = (int)fx;
    return y * __int_as_float((n + 127 + kdt) << 23);
}

// Markstein correctly-rounded division by loop-invariant d, r = RN(1/d)
// precomputed via one IEEE divide. q' == RN(x/d) bitwise for all normal x.
__device__ __forceinline__ float div_uniform(float x, float d, float r) {
    #pragma clang fp contract(off)
    float q = x * r;
    float e = __builtin_fmaf(-d, q, x);
    return __builtin_fmaf(e, r, q);
}

// ---------- R3-proven fallback steps (plain IEEE divides) ----------
__device__ __forceinline__ void step_simple(float& V, float i_t, float& spk_out,
                                            float E_L, float V_T, float Delta_T,
                                            float R, float tau_m, float V_spike,
                                            float V_reset, float dt) {
    #pragma clang fp contract(off)
    const float e  = ref_expf((V - V_T) / Delta_T);
    const float et = Delta_T * e;
    float nm = (-(V - E_L) + et);
    nm = nm + R * i_t;
    const float dV = nm / tau_m;
    V = __builtin_fmaf(dt, dV, V);
    spk_out = (V >= V_spike) ? 1.0f : 0.0f;
    V = (V >= V_spike) ? V_reset : V;
}

__device__ __forceinline__ void step_general(float& V, float& w, float i_t, float& spk_out,
                                             float E_L, float V_T, float Delta_T,
                                             float R, float tau_m, float tau_w,
                                             float a, float b,
                                             float V_spike, float V_reset, float dt) {
    #pragma clang fp contract(off)
    const float e  = ref_expf((V - V_T) / Delta_T);
    const float et = Delta_T * e;
    float nm = (-(V - E_L) + et);
    nm = __builtin_fmaf(-R, w, nm);
    nm = __builtin_fmaf(R, i_t, nm);
    const float dV = nm / tau_m;
    V = __builtin_fmaf(dt, dV, V);
    const float dwn = __builtin_fmaf(a, (V - E_L), -w);
    const float dw  = dwn / tau_w;
    w = __builtin_fmaf(dt, dw, w);
    spk_out = (V >= V_spike) ? 1.0f : 0.0f;
    const bool s = (V >= V_spike);
    V = s ? V_reset : V;
    w = s ? (w + b) : w;
}

__launch_bounds__(128, 1)
__global__ void adex_kernel(const float* __restrict__ I,
                            const float* __restrict__ params,
                            float* __restrict__ out) {
    #pragma clang fp contract(off)

    const float tau_m   = params[0];
    const float E_L     = params[1];
    const float V_T     = params[2];
    const float Delta_T = params[3];
    const float R       = params[4];
    const float tau_w   = params[5];
    const float a       = params[6];
    const float b       = params[7];
    const float V_reset = params[8];
    const float V_spike = params[9];
    const float dt      = params[10];

    const int n = blockIdx.x * blockDim.x + threadIdx.x;
    if (n >= NEUR) return;
    const int bb = n >> 10;          // / Dn
    const int dd = n & (Dn - 1);     // % Dn

    const float* Ip = I   + (size_t)bb * (size_t)(Tn * Dn) + dd;
    float*       Op = out + (size_t)bb * (size_t)(Tn * Dn) + dd;

    float V = E_L;
    float bufA[UNR], bufB[UNR];

    #pragma unroll
    for (int k = 0; k < UNR; ++k) bufA[k] = Ip[k * Dn];

    const unsigned dtBits = __float_as_uint(Delta_T);
    const bool dtPow2 = ((dtBits & 0x7FFFFFu) == 0u) && Delta_T > 0.0f;
    const bool hot = (a == 0.0f) && (b == 0.0f) && (R == 1.0f) && dtPow2;

    if (hot) {
        // -------- latency-optimized path --------
        const int   kdt = (int)((dtBits >> 23) & 0xFFu) - 127;  // log2(Delta_T)
        const float rDT = 1.0f / Delta_T;                        // exact (pow2)
        const float rTM = 1.0f / tau_m;                          // RN(1/tau_m)
        // reset-branch constants (same formulas as the live branch)
        const float xC = (V_reset - V_T) * rDT;
        const float nC = E_L - V_reset;

        float x   = (V - V_T) * rDT;   // == (V-V_T)/Delta_T bitwise
        float nEL = E_L - V;           // == -(V-E_L) bitwise (up to +0/-0; add below absorbs)

        for (int tb = 0; tb < NB; tb += 2) {
            if (tb + 1 < NB) {
                const float* p = Ip + (size_t)(tb + 1) * (UNR * Dn);
                #pragma unroll
                for (int k = 0; k < UNR; ++k) bufB[k] = p[k * Dn];
            }
            {
                float* o = Op + (size_t)tb * (UNR * Dn);
                #pragma unroll
                for (int k = 0; k < UNR; ++k) {
                    const float et = ref_expf_scaled(x, kdt);   // Delta_T * exp(x)
                    float nm = nEL + et;
                    nm = nm + bufA[k];                          // R == 1
                    const float dV = div_uniform(nm, tau_m, rTM);
                    const float Vr = __builtin_fmaf(dt, dV, V);
                    const bool  s  = (Vr >= V_spike);
                    o[k * Dn] = s ? 1.0f : 0.0f;
                    const float xn = (Vr - V_T) * rDT;          // speculative
                    const float nn = E_L - Vr;                  // speculative
                    V   = s ? V_reset : Vr;
                    x   = s ? xC : xn;
                    nEL = s ? nC : nn;
                }
            }
            if (tb + 2 < NB) {
                const float* p = Ip + (size_t)(tb + 2) * (UNR * Dn);
                #pragma unroll
                for (int k = 0; k < UNR; ++k) bufA[k] = p[k * Dn];
            }
            if (tb + 1 < NB) {
                float* o = Op + (size_t)(tb + 1) * (UNR * Dn);
                #pragma unroll
                for (int k = 0; k < UNR; ++k) {
                    const float et = ref_expf_scaled(x, kdt);
                    float nm = nEL + et;
                    nm = nm + bufB[k];
                    const float dV = div_uniform(nm, tau_m, rTM);
                    const float Vr = __builtin_fmaf(dt, dV, V);
                    const bool  s  = (Vr >= V_spike);
                    o[k * Dn] = s ? 1.0f : 0.0f;
                    const float xn = (Vr - V_T) * rDT;
                    const float nn = E_L - Vr;
                    V   = s ? V_reset : Vr;
                    x   = s ? xC : xn;
                    nEL = s ? nC : nn;
                }
            }
        }
        return;
    }

    // -------- fallback paths (R3-proven) --------
    float w = 0.0f;
    const bool simple = (a == 0.0f) && (b == 0.0f);

    if (simple) {
        for (int tb = 0; tb < NB; tb += 2) {
            if (tb + 1 < NB) {
                const float* p = Ip + (size_t)(tb + 1) * (UNR * Dn);
                #pragma unroll
                for (int k = 0; k < UNR; ++k) bufB[k] = p[k * Dn];
            }
            {
                float* o = Op + (size_t)tb * (UNR * Dn);
                #pragma unroll
                for (int k = 0; k < UNR; ++k) {
                    float spk;
                    step_simple(V, bufA[k], spk, E_L, V_T, Delta_T, R, tau_m,
                                V_spike, V_reset, dt);
                    o[k * Dn] = spk;
                }
            }
            if (tb + 2 < NB) {
                const float* p = Ip + (size_t)(tb + 2) * (UNR * Dn);
                #pragma unroll
                for (int k = 0; k < UNR; ++k) bufA[k] = p[k * Dn];
            }
            if (tb + 1 < NB) {
                float* o = Op + (size_t)(tb + 1) * (UNR * Dn);
                #pragma unroll
                for (int k = 0; k < UNR; ++k) {
                    float spk;
                    step_simple(V, bufB[k], spk, E_L, V_T, Delta_T, R, tau_m,
                                V_spike, V_reset, dt);
                    o[k * Dn] = spk;
                }
            }
        }
    } else {
        for (int tb = 0; tb < NB; tb += 2) {
            if (tb + 1 < NB) {
                const float* p = Ip + (size_t)(tb + 1) * (UNR * Dn);
                #pragma unroll
                for (int k = 0; k < UNR; ++k) bufB[k] = p[k * Dn];
            }
            {
                float* o = Op + (size_t)tb * (UNR * Dn);
                #pragma unroll
                for (int k = 0; k < UNR; ++k) {
                    float spk;
                    step_general(V, w, bufA[k], spk, E_L, V_T, Delta_T, R, tau_m,
                                 tau_w, a, b, V_spike, V_reset, dt);
                    o[k * Dn] = spk;
                }
            }
            if (tb + 2 < NB) {
                const float* p = Ip + (size_t)(tb + 2) * (UNR * Dn);
                #pragma unroll
                for (int k = 0; k < UNR; ++k) bufA[k] = p[k * Dn];
            }
            if (tb + 1 < NB) {
                float* o = Op + (size_t)(tb + 1) * (UNR * Dn);
                #pragma unroll
                for (int k = 0; k < UNR; ++k) {
                    float spk;
                    step_general(V, w, bufB[k], spk, E_L, V_T, Delta_T, R, tau_m,
                                 tau_w, a, b, V_spike, V_reset, dt);
                    o[k * Dn] = spk;
                }
            }
        }
    }
}

extern "C" void kernel_launch(void* const* d_in, const int* in_sizes, int n_in,
                              void* d_out, int out_size, void* d_ws, size_t ws_size,
                              hipStream_t stream) {
    const float* I      = (const float*)d_in[0];
    const float* params = (const float*)d_in[1];
    float*       out    = (float*)d_out;

    dim3 block(128);
    dim3 grid(NEUR / 128);  // 256 blocks -> 1 per CU
    adex_kernel<<<grid, block, 0, stream>>>(I, params, out);
}